// Round 4
// baseline (74.210 us; speedup 1.0000x reference)
//
#include <hip/hip_runtime.h>
#include <hip/hip_bf16.h>
#include <math.h>

#define BATCH 16384
#define EMBED 128
#define NPOS 10
#define NNEG 50
#define NLAB (NPOS + NNEG)   // 60

// Stable log-sigmoid: log(1/(1+e^-x)) = min(x,0) - log1p(exp(-|x|))
__device__ __forceinline__ float log_sigmoid(float x) {
    return fminf(x, 0.0f) - log1pf(__expf(-fabsf(x)));
}

__device__ __forceinline__ float dot4(float4 a, float4 b) {
    return fmaf(a.x, b.x, fmaf(a.y, b.y, fmaf(a.z, b.z, a.w * b.w)));
}

__global__ __launch_bounds__(256) void skipgram_loss_kernel(
    const int* __restrict__ input_labels,   // [B]
    const int* __restrict__ pos_labels,     // [B, P]
    const int* __restrict__ neg_labels,     // [B, N]
    const float* __restrict__ in_embed,     // [V, D]
    const float* __restrict__ out_embed,    // [V, D]
    float* __restrict__ out)                // [B]
{
    const int wave = threadIdx.x >> 6;          // 0..3
    const int lane = threadIdx.x & 63;
    const int b = blockIdx.x * 4 + wave;
    const int g = lane >> 3;                    // label group 0..7
    const int t = lane & 7;                     // slot within group

    // Center row (wave-uniform address). Lane covers elements k*32 + t*4 .. +3.
    const unsigned int coff = (unsigned int)input_labels[b] * EMBED + t * 4;
    const float4 c0 = *reinterpret_cast<const float4*>(in_embed + coff + 0 * 32);
    const float4 c1 = *reinterpret_cast<const float4*>(in_embed + coff + 1 * 32);
    const float4 c2 = *reinterpret_cast<const float4*>(in_embed + coff + 2 * 32);
    const float4 c3 = *reinterpret_cast<const float4*>(in_embed + coff + 3 * 32);

    // Preload one label per lane (slot li == lane); slots 60..63 idle.
    int lab;
    if (lane < NPOS)       lab = pos_labels[b * NPOS + lane];
    else if (lane < NLAB)  lab = neg_labels[b * NNEG + (lane - NPOS)];
    else                   lab = 0;

    // Broadcast all 8 of this group's labels; keep 32-bit element offsets so the
    // compiler emits global_load_dwordx4 with SGPR-base + 32-bit voffset.
    unsigned int roff[8];
    #pragma unroll
    for (int p = 0; p < 8; ++p)
        roff[p] = (unsigned int)__shfl(lab, p * 8 + g) * EMBED + t * 4;

    // Depth-4 rotating register pipeline (fully unrolled => static indices only)
    float4 r[4][4];
    #pragma unroll
    for (int p = 0; p < 4; ++p) {
        r[p][0] = *reinterpret_cast<const float4*>(out_embed + roff[p] + 0 * 32);
        r[p][1] = *reinterpret_cast<const float4*>(out_embed + roff[p] + 1 * 32);
        r[p][2] = *reinterpret_cast<const float4*>(out_embed + roff[p] + 2 * 32);
        r[p][3] = *reinterpret_cast<const float4*>(out_embed + roff[p] + 3 * 32);
    }

    float total = 0.0f;
    #pragma unroll
    for (int p = 0; p < 8; ++p) {
        const int s = p & 3;
        float acc = dot4(c0, r[s][0]) + dot4(c1, r[s][1])
                  + dot4(c2, r[s][2]) + dot4(c3, r[s][3]);

        // Refill this slot for pass p+4 before the reduction chain
        if (p + 4 < 8) {
            r[s][0] = *reinterpret_cast<const float4*>(out_embed + roff[p + 4] + 0 * 32);
            r[s][1] = *reinterpret_cast<const float4*>(out_embed + roff[p + 4] + 1 * 32);
            r[s][2] = *reinterpret_cast<const float4*>(out_embed + roff[p + 4] + 2 * 32);
            r[s][3] = *reinterpret_cast<const float4*>(out_embed + roff[p + 4] + 3 * 32);
        }

        // In-group butterfly (lanes differ only in bits 0..2)
        acc += __shfl_xor(acc, 1);
        acc += __shfl_xor(acc, 2);
        acc += __shfl_xor(acc, 4);

        const int li = p * 8 + g;
        const float wl = (li < NLAB) ? ((li < NPOS) ? -1.0f : 1.0f) : 0.0f;
        total += (t == 0) ? wl * log_sigmoid(acc) : 0.0f;
    }

    // Cross-group reduction (non-t0 lanes carry 0)
    total += __shfl_xor(total, 8);
    total += __shfl_xor(total, 16);
    total += __shfl_xor(total, 32);

    if (lane == 0) out[b] = total;   // = log_neg - log_pos = -loss
}

extern "C" void kernel_launch(void* const* d_in, const int* in_sizes, int n_in,
                              void* d_out, int out_size, void* d_ws, size_t ws_size,
                              hipStream_t stream) {
    const int*   input_labels = (const int*)d_in[0];
    const int*   pos_labels   = (const int*)d_in[1];
    const int*   neg_labels   = (const int*)d_in[2];
    const float* in_embed     = (const float*)d_in[3];
    const float* out_embed    = (const float*)d_in[4];
    float*       out          = (float*)d_out;

    const int blocks = BATCH / 4;  // 4096 blocks x 256 threads = 4 batch elems/block
    skipgram_loss_kernel<<<blocks, 256, 0, stream>>>(
        input_labels, pos_labels, neg_labels, in_embed, out_embed, out);
}

// Round 5
// 73.236 us; speedup vs baseline: 1.0133x; 1.0133x over previous
//
#include <hip/hip_runtime.h>
#include <hip/hip_bf16.h>
#include <math.h>

#define BATCH 16384
#define EMBED 128
#define NPOS 10
#define NNEG 50
#define NLAB (NPOS + NNEG)   // 60

// Fast stable log-sigmoid: min(x,0) - log(1 + exp(-|x|))
// __expf/__logf map to v_exp_f32/v_log_f32 (+1 mul each) — ~8 VALU total,
// ~1e-6 rel error, vs log1pf's heavyweight libm expansion.
__device__ __forceinline__ float fast_log_sigmoid(float x) {
    const float e = __expf(-fabsf(x));
    return fminf(x, 0.0f) - __logf(1.0f + e);
}

__device__ __forceinline__ float dot4(float4 a, float4 b) {
    return fmaf(a.x, b.x, fmaf(a.y, b.y, fmaf(a.z, b.z, a.w * b.w)));
}

__global__ __launch_bounds__(256) void skipgram_loss_kernel(
    const int* __restrict__ input_labels,   // [B]
    const int* __restrict__ pos_labels,     // [B, P]
    const int* __restrict__ neg_labels,     // [B, N]
    const float* __restrict__ in_embed,     // [V, D]
    const float* __restrict__ out_embed,    // [V, D]
    float* __restrict__ out)                // [B]
{
    const int wave = threadIdx.x >> 6;          // 0..3
    const int lane = threadIdx.x & 63;
    const int b = blockIdx.x * 4 + wave;
    const int g = lane >> 3;                    // label group 0..7
    const int t = lane & 7;                     // slot within group

    // Center row (wave-uniform base, 32-bit element offsets)
    const unsigned coff = (unsigned)input_labels[b] * EMBED + (unsigned)(t * 4);
    const float4 c0 = *reinterpret_cast<const float4*>(in_embed + coff);
    const float4 c1 = *reinterpret_cast<const float4*>(in_embed + coff + 32);
    const float4 c2 = *reinterpret_cast<const float4*>(in_embed + coff + 64);
    const float4 c3 = *reinterpret_cast<const float4*>(in_embed + coff + 96);

    // One label per lane slot; slots 60..63 idle.
    int lab;
    if (lane < NPOS)       lab = pos_labels[b * NPOS + lane];
    else if (lane < NLAB)  lab = neg_labels[b * NNEG + (lane - NPOS)];
    else                   lab = 0;

    // All 8 group-label offsets up front (removes shfl->addr from loop path)
    unsigned roff[8];
    #pragma unroll
    for (int p = 0; p < 8; ++p)
        roff[p] = (unsigned)__shfl(lab, p * 8 + g) * EMBED + (unsigned)(t * 4);

    // Depth-2 ping-pong: issue pass p+1's loads before consuming pass p;
    // consume current buffer immediately so only ~2 buffers are ever live.
    float4 u0 = *reinterpret_cast<const float4*>(out_embed + roff[0]);
    float4 u1 = *reinterpret_cast<const float4*>(out_embed + roff[0] + 32);
    float4 u2 = *reinterpret_cast<const float4*>(out_embed + roff[0] + 64);
    float4 u3 = *reinterpret_cast<const float4*>(out_embed + roff[0] + 96);

    float total = 0.0f;
    #pragma unroll
    for (int p = 0; p < 8; ++p) {
        float4 n0, n1, n2, n3;
        if (p < 7) {
            n0 = *reinterpret_cast<const float4*>(out_embed + roff[p + 1]);
            n1 = *reinterpret_cast<const float4*>(out_embed + roff[p + 1] + 32);
            n2 = *reinterpret_cast<const float4*>(out_embed + roff[p + 1] + 64);
            n3 = *reinterpret_cast<const float4*>(out_embed + roff[p + 1] + 96);
        }

        float acc = dot4(c0, u0) + dot4(c1, u1) + dot4(c2, u2) + dot4(c3, u3);

        // In-group butterfly (lanes differ in bits 0..2)
        acc += __shfl_xor(acc, 1);
        acc += __shfl_xor(acc, 2);
        acc += __shfl_xor(acc, 4);

        const int li = p * 8 + g;
        const float wl = (li < NLAB) ? ((li < NPOS) ? -1.0f : 1.0f) : 0.0f;
        total += (t == 0) ? wl * fast_log_sigmoid(acc) : 0.0f;

        if (p < 7) { u0 = n0; u1 = n1; u2 = n2; u3 = n3; }
    }

    // Cross-group reduction (non-t0 lanes carry 0)
    total += __shfl_xor(total, 8);
    total += __shfl_xor(total, 16);
    total += __shfl_xor(total, 32);

    if (lane == 0) out[b] = total;   // = log_neg - log_pos = -loss
}

extern "C" void kernel_launch(void* const* d_in, const int* in_sizes, int n_in,
                              void* d_out, int out_size, void* d_ws, size_t ws_size,
                              hipStream_t stream) {
    const int*   input_labels = (const int*)d_in[0];
    const int*   pos_labels   = (const int*)d_in[1];
    const int*   neg_labels   = (const int*)d_in[2];
    const float* in_embed     = (const float*)d_in[3];
    const float* out_embed    = (const float*)d_in[4];
    float*       out          = (float*)d_out;

    const int blocks = BATCH / 4;  // 4096 blocks x 256 threads
    skipgram_loss_kernel<<<blocks, 256, 0, stream>>>(
        input_labels, pos_labels, neg_labels, in_embed, out_embed, out);
}

// Round 6
// 50.452 us; speedup vs baseline: 1.4709x; 1.4516x over previous
//
#include <hip/hip_runtime.h>
#include <hip/hip_bf16.h>
#include <math.h>

#define VOCAB 100000
#define EMBED 128
#define BATCH 16384
#define NPOS 10
#define NNEG 50
#define NLAB (NPOS + NNEG)   // 60

// ---------- helpers ----------

// Fast stable log-sigmoid: min(x,0) - log(1 + exp(-|x|))
__device__ __forceinline__ float fast_log_sigmoid(float x) {
    const float e = __expf(-fabsf(x));
    return fminf(x, 0.0f) - __logf(1.0f + e);
}

__device__ __forceinline__ float dot4(float4 a, float4 b) {
    return fmaf(a.x, b.x, fmaf(a.y, b.y, fmaf(a.z, b.z, a.w * b.w)));
}

// f32 -> bf16 bits, round-to-nearest-even (inputs are finite gaussians; no NaN path)
__device__ __forceinline__ unsigned bf16rne(float f) {
    unsigned u = __float_as_uint(f);
    return (u + 0x7fffu + ((u >> 16) & 1u)) >> 16;
}
__device__ __forceinline__ unsigned pack2(float lo, float hi) {
    return bf16rne(lo) | (bf16rne(hi) << 16);
}

// dot of 8 consecutive elems: x = elems e..e+3, y = e+4..e+7 (f32 center),
// v = uint4 holding 8 packed bf16 elems e..e+7 (lo,hi per uint)
__device__ __forceinline__ float dot8(float4 x, float4 y, uint4 v) {
    const float f0 = __uint_as_float(v.x << 16);
    const float f1 = __uint_as_float(v.x & 0xffff0000u);
    const float f2 = __uint_as_float(v.y << 16);
    const float f3 = __uint_as_float(v.y & 0xffff0000u);
    const float f4 = __uint_as_float(v.z << 16);
    const float f5 = __uint_as_float(v.z & 0xffff0000u);
    const float f6 = __uint_as_float(v.w << 16);
    const float f7 = __uint_as_float(v.w & 0xffff0000u);
    const float a = fmaf(x.x, f0, fmaf(x.y, f1, fmaf(x.z, f2, x.w * f3)));
    const float b = fmaf(y.x, f4, fmaf(y.y, f5, fmaf(y.z, f6, y.w * f7)));
    return a + b;
}

// ---------- pass 1: out_embed f32 -> packed bf16 (2 per uint) ----------
__global__ __launch_bounds__(256) void cvt_bf16_kernel(
    const float* __restrict__ src, unsigned* __restrict__ dst, int n8)
{
    int i = blockIdx.x * 256 + threadIdx.x;
    const int stride = gridDim.x * 256;
    const float4* __restrict__ s4 = reinterpret_cast<const float4*>(src);
    uint4* __restrict__ d4 = reinterpret_cast<uint4*>(dst);
    for (; i < n8; i += stride) {
        const float4 a = s4[2 * i];
        const float4 b = s4[2 * i + 1];
        uint4 o;
        o.x = pack2(a.x, a.y);
        o.y = pack2(a.z, a.w);
        o.z = pack2(b.x, b.y);
        o.w = pack2(b.z, b.w);
        d4[i] = o;
    }
}

// ---------- pass 2: gather + loss, bf16 out_embed rows (256 B/row) ----------
__global__ __launch_bounds__(256) void skipgram_loss_bf16_kernel(
    const int* __restrict__ input_labels,
    const int* __restrict__ pos_labels,
    const int* __restrict__ neg_labels,
    const float* __restrict__ in_embed,
    const unsigned* __restrict__ out_bf,   // [V][64] uints (2 bf16 each)
    float* __restrict__ out)
{
    const int wave = threadIdx.x >> 6;
    const int lane = threadIdx.x & 63;
    const int b = blockIdx.x * 4 + wave;
    const int g = lane >> 3;               // label group 0..7
    const int t = lane & 7;                // slot within group

    // Center row in f32. Lane t needs elems [t*8..t*8+7] and [64+t*8..+7].
    const float* __restrict__ crow = in_embed + (unsigned)input_labels[b] * EMBED;
    const float4 ca = *reinterpret_cast<const float4*>(crow + t * 8);
    const float4 cb = *reinterpret_cast<const float4*>(crow + t * 8 + 4);
    const float4 cc = *reinterpret_cast<const float4*>(crow + 64 + t * 8);
    const float4 cd = *reinterpret_cast<const float4*>(crow + 64 + t * 8 + 4);

    int lab;
    if (lane < NPOS)       lab = pos_labels[b * NPOS + lane];
    else if (lane < NLAB)  lab = neg_labels[b * NNEG + (lane - NPOS)];
    else                   lab = 0;

    // uint-index offsets: row*64 + t*4 (lane reads uint4 = 8 bf16 at elem t*8)
    unsigned roff[8];
    #pragma unroll
    for (int p = 0; p < 8; ++p)
        roff[p] = (unsigned)__shfl(lab, p * 8 + g) * 64u + (unsigned)(t * 4);

    // Depth-2 ping-pong; 2 uint4 loads per row (halves at +0 and +32 uints)
    uint4 u0 = *reinterpret_cast<const uint4*>(out_bf + roff[0]);
    uint4 u1 = *reinterpret_cast<const uint4*>(out_bf + roff[0] + 32);

    float total = 0.0f;
    #pragma unroll
    for (int p = 0; p < 8; ++p) {
        uint4 n0, n1;
        if (p < 7) {
            n0 = *reinterpret_cast<const uint4*>(out_bf + roff[p + 1]);
            n1 = *reinterpret_cast<const uint4*>(out_bf + roff[p + 1] + 32);
        }

        float acc = dot8(ca, cb, u0) + dot8(cc, cd, u1);

        acc += __shfl_xor(acc, 1);
        acc += __shfl_xor(acc, 2);
        acc += __shfl_xor(acc, 4);

        const int li = p * 8 + g;
        const float wl = (li < NLAB) ? ((li < NPOS) ? -1.0f : 1.0f) : 0.0f;
        total += (t == 0) ? wl * fast_log_sigmoid(acc) : 0.0f;

        if (p < 7) { u0 = n0; u1 = n1; }
    }

    total += __shfl_xor(total, 8);
    total += __shfl_xor(total, 16);
    total += __shfl_xor(total, 32);

    if (lane == 0) out[b] = total;   // = log_neg - log_pos = -loss
}

// ---------- fallback: round-5 all-f32 gather (if ws too small) ----------
__global__ __launch_bounds__(256) void skipgram_loss_f32_kernel(
    const int* __restrict__ input_labels,
    const int* __restrict__ pos_labels,
    const int* __restrict__ neg_labels,
    const float* __restrict__ in_embed,
    const float* __restrict__ out_embed,
    float* __restrict__ out)
{
    const int wave = threadIdx.x >> 6;
    const int lane = threadIdx.x & 63;
    const int b = blockIdx.x * 4 + wave;
    const int g = lane >> 3;
    const int t = lane & 7;

    const unsigned coff = (unsigned)input_labels[b] * EMBED + (unsigned)(t * 4);
    const float4 c0 = *reinterpret_cast<const float4*>(in_embed + coff);
    const float4 c1 = *reinterpret_cast<const float4*>(in_embed + coff + 32);
    const float4 c2 = *reinterpret_cast<const float4*>(in_embed + coff + 64);
    const float4 c3 = *reinterpret_cast<const float4*>(in_embed + coff + 96);

    int lab;
    if (lane < NPOS)       lab = pos_labels[b * NPOS + lane];
    else if (lane < NLAB)  lab = neg_labels[b * NNEG + (lane - NPOS)];
    else                   lab = 0;

    unsigned roff[8];
    #pragma unroll
    for (int p = 0; p < 8; ++p)
        roff[p] = (unsigned)__shfl(lab, p * 8 + g) * EMBED + (unsigned)(t * 4);

    float4 u0 = *reinterpret_cast<const float4*>(out_embed + roff[0]);
    float4 u1 = *reinterpret_cast<const float4*>(out_embed + roff[0] + 32);
    float4 u2 = *reinterpret_cast<const float4*>(out_embed + roff[0] + 64);
    float4 u3 = *reinterpret_cast<const float4*>(out_embed + roff[0] + 96);

    float total = 0.0f;
    #pragma unroll
    for (int p = 0; p < 8; ++p) {
        float4 n0, n1, n2, n3;
        if (p < 7) {
            n0 = *reinterpret_cast<const float4*>(out_embed + roff[p + 1]);
            n1 = *reinterpret_cast<const float4*>(out_embed + roff[p + 1] + 32);
            n2 = *reinterpret_cast<const float4*>(out_embed + roff[p + 1] + 64);
            n3 = *reinterpret_cast<const float4*>(out_embed + roff[p + 1] + 96);
        }
        float acc = dot4(c0, u0) + dot4(c1, u1) + dot4(c2, u2) + dot4(c3, u3);
        acc += __shfl_xor(acc, 1);
        acc += __shfl_xor(acc, 2);
        acc += __shfl_xor(acc, 4);
        const int li = p * 8 + g;
        const float wl = (li < NLAB) ? ((li < NPOS) ? -1.0f : 1.0f) : 0.0f;
        total += (t == 0) ? wl * fast_log_sigmoid(acc) : 0.0f;
        if (p < 7) { u0 = n0; u1 = n1; u2 = n2; u3 = n3; }
    }

    total += __shfl_xor(total, 8);
    total += __shfl_xor(total, 16);
    total += __shfl_xor(total, 32);

    if (lane == 0) out[b] = total;
}

extern "C" void kernel_launch(void* const* d_in, const int* in_sizes, int n_in,
                              void* d_out, int out_size, void* d_ws, size_t ws_size,
                              hipStream_t stream) {
    const int*   input_labels = (const int*)d_in[0];
    const int*   pos_labels   = (const int*)d_in[1];
    const int*   neg_labels   = (const int*)d_in[2];
    const float* in_embed     = (const float*)d_in[3];
    const float* out_embed    = (const float*)d_in[4];
    float*       out          = (float*)d_out;

    const size_t need = (size_t)VOCAB * EMBED * sizeof(unsigned short); // 25.6 MB
    const int blocks = BATCH / 4;  // 4096 blocks x 256 threads

    if (ws_size >= need) {
        unsigned* out_bf = (unsigned*)d_ws;
        const int n8 = VOCAB * EMBED / 8;  // 1.6M 8-element chunks
        cvt_bf16_kernel<<<2048, 256, 0, stream>>>(out_embed, out_bf, n8);
        skipgram_loss_bf16_kernel<<<blocks, 256, 0, stream>>>(
            input_labels, pos_labels, neg_labels, in_embed, out_bf, out);
    } else {
        skipgram_loss_f32_kernel<<<blocks, 256, 0, stream>>>(
            input_labels, pos_labels, neg_labels, in_embed, out_embed, out);
    }
}